// Round 2
// baseline (22307.982 us; speedup 1.0000x reference)
//
#include <hip/hip_runtime.h>

#define BB 4
#define CC 64
#define NNN 4096
#define OO 64
#define KK 20
#define EPSF 1e-5f

// ---------------- K1: xx[n] = sum_c x[c][n]^2 in f64 ----------------
__global__ __launch_bounds__(256) void xx_kernel(const float* __restrict__ x, double* __restrict__ xx) {
    int g = blockIdx.x * 256 + threadIdx.x;          // 0..B*N-1
    int b = g >> 12, n = g & (NNN - 1);
    const float* xp = x + (size_t)b * CC * NNN + n;
    double s = 0.0;
    for (int c = 0; c < CC; ++c) {
        double v = (double)xp[(size_t)c * NNN];
        s += v * v;
    }
    xx[g] = s;
}

// ---------------- K2: per-point projections A = x*w1a^T, Bv = x*(w1b-w1a)^T ----------------
__global__ __launch_bounds__(256) void proj_kernel(const float* __restrict__ x, const float* __restrict__ w1,
                                                   float* __restrict__ A, float* __restrict__ Bv) {
    __shared__ float xs[CC][64];       // [c][p]
    __shared__ float ws1[OO][129];     // padded
    int tid = threadIdx.x;
    int b = blockIdx.x >> 6;
    int p0 = (blockIdx.x & 63) << 6;
    const float* xb = x + (size_t)b * CC * NNN;
    for (int i = tid; i < CC * 16; i += 256) {
        int c = i >> 4, q = i & 15;
        *(float4*)&xs[c][q * 4] = *(const float4*)(xb + (size_t)c * NNN + p0 + q * 4);
    }
    for (int i = tid; i < OO * 32; i += 256) {
        int o = i >> 5, q = i & 31;
        float4 v = *(const float4*)(w1 + o * 128 + q * 4);
        ws1[o][q * 4 + 0] = v.x; ws1[o][q * 4 + 1] = v.y;
        ws1[o][q * 4 + 2] = v.z; ws1[o][q * 4 + 3] = v.w;
    }
    __syncthreads();
    int ti = tid >> 4, tj = tid & 15;
    float aA[4][4] = {{0.f}}, aD[4][4] = {{0.f}};
    for (int c = 0; c < CC; ++c) {
        float4 xv4 = *(const float4*)&xs[c][ti * 4];
        float xv[4] = {xv4.x, xv4.y, xv4.z, xv4.w};
        #pragma unroll
        for (int oo = 0; oo < 4; ++oo) {
            float wa = ws1[tj * 4 + oo][c];
            float wd = ws1[tj * 4 + oo][64 + c] - wa;
            #pragma unroll
            for (int pp = 0; pp < 4; ++pp) {
                aA[pp][oo] = fmaf(xv[pp], wa, aA[pp][oo]);
                aD[pp][oo] = fmaf(xv[pp], wd, aD[pp][oo]);
            }
        }
    }
    size_t base = ((size_t)b * NNN + p0) * 64;
    #pragma unroll
    for (int pp = 0; pp < 4; ++pp) {
        int p = ti * 4 + pp;
        *(float4*)(A  + base + (size_t)p * 64 + tj * 4) = make_float4(aA[pp][0], aA[pp][1], aA[pp][2], aA[pp][3]);
        *(float4*)(Bv + base + (size_t)p * 64 + tj * 4) = make_float4(aD[pp][0], aD[pp][1], aD[pp][2], aD[pp][3]);
    }
}

// ---------------- K3: fused f64 distances + per-thread register top-20 ----------------
// 1024 blocks (4/CU). Block = 16 rows x 4096 cands. Thread = (row r, cand-group g):
// r = lane&15, g = wave*4 + (lane>>4); each thread scans 256 candidates, keeps a
// register-resident sorted top-20 (insert = replace-min + unrolled bubble pass).
// 4-step LDS merge tree reduces 16 lists/row -> 1, once per block.
__global__ __launch_bounds__(256, 4) void knn_kernel(const float* __restrict__ x, const double* __restrict__ xx,
                                                     int* __restrict__ idxOut) {
    __shared__ __align__(16) char smem[37376];
    float  (*rowT)[16]  = (float(*)[16])smem;              // [64][16] f32   4096 B
    double (*candT)[64] = (double(*)[64])(smem + 4096);    // [64][64] f64  32768 B
    double *xxc         = (double*)(smem + 4096 + 32768);  // [64]           512 B
    // merge-phase aliases (stage buffers dead by then):
    double (*mD)[KK] = (double(*)[KK])smem;                // [128][20] f64 20480 B
    int    (*mI)[KK] = (int(*)[KK])(smem + 20480);         // [128][20] int 10240 B

    int tid  = threadIdx.x;
    int lane = tid & 63, w = tid >> 6;
    int r = lane & 15;                // row within block
    int g = w * 4 + (lane >> 4);      // candidate group 0..15
    int b  = blockIdx.x >> 8;
    int r0 = (blockIdx.x & 255) * 16;
    const float* xb = x + (size_t)b * CC * NNN;

    for (int i = tid; i < CC * 16; i += 256) {
        int c = i >> 4, rr = i & 15;
        rowT[c][rr] = xb[(size_t)c * NNN + r0 + rr];
    }
    double xr = xx[b * NNN + r0 + r];

    double lD[KK]; int lI[KK];
    #pragma unroll
    for (int q = 0; q < KK; ++q) { lD[q] = -1.0e300; lI[q] = 0; }

    auto ins = [&](double d, int jg) {
        lD[0] = d; lI[0] = jg;
        #pragma unroll
        for (int q = 0; q < KK - 1; ++q) {
            if (lD[q] > lD[q + 1]) {
                double td = lD[q]; lD[q] = lD[q + 1]; lD[q + 1] = td;
                int t2 = lI[q]; lI[q] = lI[q + 1]; lI[q + 1] = t2;
            }
        }
    };

    for (int j0 = 0; j0 < NNN; j0 += 64) {
        __syncthreads();                       // candT readers of prev tile done
        for (int i = tid; i < CC * 64; i += 256) {
            int c = i >> 6, jj = i & 63;
            candT[c][jj] = (double)xb[(size_t)c * NNN + j0 + jj];
        }
        if (tid < 64) xxc[tid] = xx[b * NNN + j0 + tid];
        __syncthreads();
        double a0 = 0.0, a1 = 0.0, a2 = 0.0, a3 = 0.0;
        for (int c = 0; c < CC; ++c) {
            double rv = (double)rowT[c][r];
            double2 c01 = *(const double2*)&candT[c][g * 4];
            double2 c23 = *(const double2*)&candT[c][g * 4 + 2];
            a0 = fma(rv, c01.x, a0);
            a1 = fma(rv, c01.y, a1);
            a2 = fma(rv, c23.x, a2);
            a3 = fma(rv, c23.y, a3);
        }
        double dd[4] = {a0, a1, a2, a3};
        #pragma unroll
        for (int j = 0; j < 4; ++j) {
            double d = 2.0 * dd[j] - xr - xxc[g * 4 + j];
            int jg = j0 + g * 4 + j;
            if (d > lD[0]) ins(d, jg);
        }
    }

    // merge tree: step s, groups that are multiples of 2^s pair up; odd half publishes.
    for (int s = 0; s < 4; ++s) {
        __syncthreads();                       // also protects smem alias on s=0
        int bit = 1 << s;
        bool alive = (g & (bit - 1)) == 0;
        bool pub = alive && (g & bit);
        int slot = (g >> (s + 1)) * 16 + r;    // same for publisher and its merger
        if (pub) {
            #pragma unroll
            for (int q = 0; q < KK; ++q) { mD[slot][q] = lD[q]; mI[slot][q] = lI[q]; }
        }
        __syncthreads();
        if (alive && !pub) {
            for (int q = 0; q < KK; ++q) {
                double pd = mD[slot][q]; int pi = mI[slot][q];
                if (pd > lD[0]) ins(pd, pi);
            }
        }
    }
    if (g == 0) {
        for (int q = 0; q < KK; ++q)
            idxOut[((size_t)b * NNN + r0 + r) * KK + q] = lI[q];
    }
}

// ---------------- K4: h1 = relu(bn1(A[nb]+Bv[n])); h2 = relu(bn2(h1·w2^T)); max over k ----------------
__global__ __launch_bounds__(256) void edge_kernel(const float* __restrict__ A, const float* __restrict__ Bv,
        const int* __restrict__ idx, const float* __restrict__ w2,
        const float* __restrict__ g1, const float* __restrict__ be1, const float* __restrict__ m1, const float* __restrict__ v1,
        const float* __restrict__ g2, const float* __restrict__ be2, const float* __restrict__ m2, const float* __restrict__ v2,
        float* __restrict__ out) {
    __shared__ float h1buf[4][KK][64];
    __shared__ float resT[64][33];
    int tid = threadIdx.x;
    int lane = tid & 63, w = tid >> 6;
    int b = blockIdx.x >> 7;
    int n0 = (blockIdx.x & 127) * 32;
    float s1 = g1[lane] * rsqrtf(v1[lane] + EPSF);
    float bb1 = be1[lane] - m1[lane] * s1;
    float s2 = g2[lane] * rsqrtf(v2[lane] + EPSF);
    float bb2 = be2[lane] - m2[lane] * s2;
    float w2r[64];
    #pragma unroll
    for (int o = 0; o < 64; ++o) w2r[o] = w2[lane * 64 + o];
    for (int p = 0; p < 8; ++p) {
        int n = n0 + w * 8 + p;
        size_t pb = (size_t)b * NNN + n;
        float bv = Bv[pb * 64 + lane];
        const int* ip = idx + pb * KK;
        #pragma unroll
        for (int k = 0; k < KK; ++k) {
            int nb = ip[k];
            float av = A[((size_t)b * NNN + nb) * 64 + lane];
            h1buf[w][k][lane] = fmaxf(0.f, fmaf(av + bv, s1, bb1));
        }
        __syncthreads();
        float mx = -1e30f;
        for (int k = 0; k < KK; ++k) {
            const float4* hb = (const float4*)&h1buf[w][k][0];
            float dot = 0.f;
            #pragma unroll
            for (int o4 = 0; o4 < 16; ++o4) {
                float4 h = hb[o4];
                dot = fmaf(w2r[o4 * 4 + 0], h.x, dot);
                dot = fmaf(w2r[o4 * 4 + 1], h.y, dot);
                dot = fmaf(w2r[o4 * 4 + 2], h.z, dot);
                dot = fmaf(w2r[o4 * 4 + 3], h.w, dot);
            }
            mx = fmaxf(mx, fmaxf(0.f, fmaf(dot, s2, bb2)));
        }
        resT[lane][w * 8 + p] = mx;
        __syncthreads();
    }
    for (int i = tid; i < 64 * 32; i += 256) {
        int o2 = i >> 5, pp = i & 31;
        out[((size_t)b * 64 + o2) * NNN + n0 + pp] = resT[o2][pp];
    }
}

extern "C" void kernel_launch(void* const* d_in, const int* in_sizes, int n_in,
                              void* d_out, int out_size, void* d_ws, size_t ws_size,
                              hipStream_t stream) {
    const float* x   = (const float*)d_in[0];
    const float* w1  = (const float*)d_in[1];
    const float* g1  = (const float*)d_in[2];
    const float* be1 = (const float*)d_in[3];
    const float* m1  = (const float*)d_in[4];
    const float* v1  = (const float*)d_in[5];
    const float* w2  = (const float*)d_in[6];
    const float* g2  = (const float*)d_in[7];
    const float* be2 = (const float*)d_in[8];
    const float* m2  = (const float*)d_in[9];
    const float* v2  = (const float*)d_in[10];
    // ws layout: xx f64 (128KB) | A f32 (4MB) | Bv f32 (4MB) | idx i32 (1.25MB)
    char* ws = (char*)d_ws;
    double* xx = (double*)ws;
    float*  A  = (float*)(ws + 131072);
    float*  Bv = (float*)(ws + 131072 + 4194304);
    int*    nidx = (int*)(ws + 131072 + 2 * 4194304);
    float*  out = (float*)d_out;

    hipLaunchKernelGGL(xx_kernel,   dim3(BB * NNN / 256), dim3(256), 0, stream, x, xx);
    hipLaunchKernelGGL(proj_kernel, dim3(BB * (NNN / 64)), dim3(256), 0, stream, x, w1, A, Bv);
    hipLaunchKernelGGL(knn_kernel,  dim3(BB * (NNN / 16)), dim3(256), 0, stream, x, xx, nidx);
    hipLaunchKernelGGL(edge_kernel, dim3(BB * (NNN / 32)), dim3(256), 0, stream,
                       A, Bv, nidx, w2, g1, be1, m1, v1, g2, be2, m2, v2, out);
}

// Round 3
// 19981.874 us; speedup vs baseline: 1.1164x; 1.1164x over previous
//
#include <hip/hip_runtime.h>

#define BB 4
#define CC 64
#define NNN 4096
#define OO 64
#define KK 20
#define EPSF 1e-5f

// ---------------- K1: xx[n] = sum_c x[c][n]^2 in f64 ----------------
__global__ __launch_bounds__(256) void xx_kernel(const float* __restrict__ x, double* __restrict__ xx) {
    int g = blockIdx.x * 256 + threadIdx.x;          // 0..B*N-1
    int b = g >> 12, n = g & (NNN - 1);
    const float* xp = x + (size_t)b * CC * NNN + n;
    double s = 0.0;
    for (int c = 0; c < CC; ++c) {
        double v = (double)xp[(size_t)c * NNN];
        s += v * v;
    }
    xx[g] = s;
}

// ---------------- K2: per-point projections A = x*w1a^T, Bv = x*(w1b-w1a)^T ----------------
__global__ __launch_bounds__(256) void proj_kernel(const float* __restrict__ x, const float* __restrict__ w1,
                                                   float* __restrict__ A, float* __restrict__ Bv) {
    __shared__ float xs[CC][64];       // [c][p]
    __shared__ float ws1[OO][129];     // padded
    int tid = threadIdx.x;
    int b = blockIdx.x >> 6;
    int p0 = (blockIdx.x & 63) << 6;
    const float* xb = x + (size_t)b * CC * NNN;
    for (int i = tid; i < CC * 16; i += 256) {
        int c = i >> 4, q = i & 15;
        *(float4*)&xs[c][q * 4] = *(const float4*)(xb + (size_t)c * NNN + p0 + q * 4);
    }
    for (int i = tid; i < OO * 32; i += 256) {
        int o = i >> 5, q = i & 31;
        float4 v = *(const float4*)(w1 + o * 128 + q * 4);
        ws1[o][q * 4 + 0] = v.x; ws1[o][q * 4 + 1] = v.y;
        ws1[o][q * 4 + 2] = v.z; ws1[o][q * 4 + 3] = v.w;
    }
    __syncthreads();
    int ti = tid >> 4, tj = tid & 15;
    float aA[4][4] = {{0.f}}, aD[4][4] = {{0.f}};
    for (int c = 0; c < CC; ++c) {
        float4 xv4 = *(const float4*)&xs[c][ti * 4];
        float xv[4] = {xv4.x, xv4.y, xv4.z, xv4.w};
        #pragma unroll
        for (int oo = 0; oo < 4; ++oo) {
            float wa = ws1[tj * 4 + oo][c];
            float wd = ws1[tj * 4 + oo][64 + c] - wa;
            #pragma unroll
            for (int pp = 0; pp < 4; ++pp) {
                aA[pp][oo] = fmaf(xv[pp], wa, aA[pp][oo]);
                aD[pp][oo] = fmaf(xv[pp], wd, aD[pp][oo]);
            }
        }
    }
    size_t base = ((size_t)b * NNN + p0) * 64;
    #pragma unroll
    for (int pp = 0; pp < 4; ++pp) {
        int p = ti * 4 + pp;
        *(float4*)(A  + base + (size_t)p * 64 + tj * 4) = make_float4(aA[pp][0], aA[pp][1], aA[pp][2], aA[pp][3]);
        *(float4*)(Bv + base + (size_t)p * 64 + tj * 4) = make_float4(aD[pp][0], aD[pp][1], aD[pp][2], aD[pp][3]);
    }
}

// ---------------- K3: fused f64 distances + register top-20 (named scalars, spill-proof) ----------------
// 1024 blocks (4/CU). Block = 16 rows x 4096 cands. Thread (r = lane&15, g = w*4+(lane>>4))
// scans 256 candidates, keeps sorted top-20 as 20 NAMED u64 registers:
// key = monotonic-bits(f64 dist) with low 12 bits = 4095-j  (index rides in the key).
// Insert = replace-min + unrolled 19-step compare-swap chain. 4-step LDS merge tree.

__device__ __forceinline__ unsigned long long packkey(double d, int j) {
    unsigned long long u = __double_as_longlong(d);
    u ^= (unsigned long long)((long long)u >> 63) | 0x8000000000000000ULL;
    return (u & ~0xFFFULL) | (unsigned long long)(4095 - j);
}

#define LIST20(M) M(0) M(1) M(2) M(3) M(4) M(5) M(6) M(7) M(8) M(9) \
                  M(10) M(11) M(12) M(13) M(14) M(15) M(16) M(17) M(18) M(19)

#define CSW(A,B) { if (K##A > K##B) { unsigned long long _t = K##A; K##A = K##B; K##B = _t; } }
#define INS20(k) do { K0 = (k); \
    CSW(0,1) CSW(1,2) CSW(2,3) CSW(3,4) CSW(4,5) CSW(5,6) CSW(6,7) CSW(7,8) CSW(8,9) CSW(9,10) \
    CSW(10,11) CSW(11,12) CSW(12,13) CSW(13,14) CSW(14,15) CSW(15,16) CSW(16,17) CSW(17,18) CSW(18,19) \
} while (0)

__global__ __launch_bounds__(256, 4) void knn_kernel(const float* __restrict__ x, const double* __restrict__ xx,
                                                     int* __restrict__ idxOut) {
    __shared__ __align__(16) char smem[37376];
    float  (*rowT)[16]  = (float(*)[16])smem;              // [64][16] f32   4096 B
    double (*candT)[64] = (double(*)[64])(smem + 4096);    // [64][64] f64  32768 B
    double *xxc         = (double*)(smem + 4096 + 32768);  // [64]           512 B
    // merge-phase alias (stage buffers dead by then):
    unsigned long long (*mK)[KK] = (unsigned long long(*)[KK])smem;  // [128][20] 20480 B

    int tid  = threadIdx.x;
    int lane = tid & 63, w = tid >> 6;
    int r = lane & 15;                // row within block
    int g = w * 4 + (lane >> 4);      // candidate group 0..15
    int b  = blockIdx.x >> 8;
    int r0 = (blockIdx.x & 255) * 16;
    const float* xb = x + (size_t)b * CC * NNN;

    for (int i = tid; i < CC * 16; i += 256) {
        int c = i >> 4, rr = i & 15;
        rowT[c][rr] = xb[(size_t)c * NNN + r0 + rr];
    }
    double xr = xx[b * NNN + r0 + r];

    unsigned long long K0=0,K1=0,K2=0,K3=0,K4=0,K5=0,K6=0,K7=0,K8=0,K9=0,
                       K10=0,K11=0,K12=0,K13=0,K14=0,K15=0,K16=0,K17=0,K18=0,K19=0;

    for (int j0 = 0; j0 < NNN; j0 += 64) {
        __syncthreads();                       // candT readers of prev tile done
        for (int i = tid; i < CC * 64; i += 256) {
            int c = i >> 6, jj = i & 63;
            candT[c][jj] = (double)xb[(size_t)c * NNN + j0 + jj];
        }
        if (tid < 64) xxc[tid] = xx[b * NNN + j0 + tid];
        __syncthreads();
        double a0 = 0.0, a1 = 0.0, a2 = 0.0, a3 = 0.0;
        for (int c = 0; c < CC; ++c) {
            double rv = (double)rowT[c][r];
            double2 c01 = *(const double2*)&candT[c][g * 4];
            double2 c23 = *(const double2*)&candT[c][g * 4 + 2];
            a0 = fma(rv, c01.x, a0);
            a1 = fma(rv, c01.y, a1);
            a2 = fma(rv, c23.x, a2);
            a3 = fma(rv, c23.y, a3);
        }
        {
            double d; unsigned long long k;
            d = 2.0 * a0 - xr - xxc[g * 4 + 0]; k = packkey(d, j0 + g * 4 + 0); if (k > K0) INS20(k);
            d = 2.0 * a1 - xr - xxc[g * 4 + 1]; k = packkey(d, j0 + g * 4 + 1); if (k > K0) INS20(k);
            d = 2.0 * a2 - xr - xxc[g * 4 + 2]; k = packkey(d, j0 + g * 4 + 2); if (k > K0) INS20(k);
            d = 2.0 * a3 - xr - xxc[g * 4 + 3]; k = packkey(d, j0 + g * 4 + 3); if (k > K0) INS20(k);
        }
    }

    // merge tree: step s, groups that are multiples of 2^s pair up; odd half publishes.
    for (int s = 0; s < 4; ++s) {
        __syncthreads();                       // also protects smem alias on s=0
        int bit = 1 << s;
        bool alive = (g & (bit - 1)) == 0;
        bool pub = alive && (g & bit);
        int slot = (g >> (s + 1)) * 16 + r;    // same for publisher and its merger
        if (pub) {
            #define PUBQ(Q) mK[slot][Q] = K##Q;
            LIST20(PUBQ)
            #undef PUBQ
        }
        __syncthreads();
        if (alive && !pub) {
            for (int q = KK - 1; q >= 0; --q) {          // partner sorted asc: scan from best
                unsigned long long pk = mK[slot][q];
                if (pk <= K0) break;
                INS20(pk);
            }
        }
    }
    if (g == 0) {
        int* op = idxOut + ((size_t)b * NNN + r0 + r) * KK;
        #define OUTQ(Q) op[Q] = 4095 - (int)(K##Q & 0xFFFULL);
        LIST20(OUTQ)
        #undef OUTQ
    }
}

// ---------------- K4: h1 = relu(bn1(A[nb]+Bv[n])); h2 = relu(bn2(h1·w2^T)); max over k ----------------
__global__ __launch_bounds__(256) void edge_kernel(const float* __restrict__ A, const float* __restrict__ Bv,
        const int* __restrict__ idx, const float* __restrict__ w2,
        const float* __restrict__ g1, const float* __restrict__ be1, const float* __restrict__ m1, const float* __restrict__ v1,
        const float* __restrict__ g2, const float* __restrict__ be2, const float* __restrict__ m2, const float* __restrict__ v2,
        float* __restrict__ out) {
    __shared__ float h1buf[4][KK][64];
    __shared__ float resT[64][33];
    int tid = threadIdx.x;
    int lane = tid & 63, w = tid >> 6;
    int b = blockIdx.x >> 7;
    int n0 = (blockIdx.x & 127) * 32;
    float s1 = g1[lane] * rsqrtf(v1[lane] + EPSF);
    float bb1 = be1[lane] - m1[lane] * s1;
    float s2 = g2[lane] * rsqrtf(v2[lane] + EPSF);
    float bb2 = be2[lane] - m2[lane] * s2;
    float w2r[64];
    #pragma unroll
    for (int o = 0; o < 64; ++o) w2r[o] = w2[lane * 64 + o];
    for (int p = 0; p < 8; ++p) {
        int n = n0 + w * 8 + p;
        size_t pb = (size_t)b * NNN + n;
        float bv = Bv[pb * 64 + lane];
        const int* ip = idx + pb * KK;
        #pragma unroll
        for (int k = 0; k < KK; ++k) {
            int nb = ip[k];
            float av = A[((size_t)b * NNN + nb) * 64 + lane];
            h1buf[w][k][lane] = fmaxf(0.f, fmaf(av + bv, s1, bb1));
        }
        __syncthreads();
        float mx = -1e30f;
        for (int k = 0; k < KK; ++k) {
            const float4* hb = (const float4*)&h1buf[w][k][0];
            float dot = 0.f;
            #pragma unroll
            for (int o4 = 0; o4 < 16; ++o4) {
                float4 h = hb[o4];
                dot = fmaf(w2r[o4 * 4 + 0], h.x, dot);
                dot = fmaf(w2r[o4 * 4 + 1], h.y, dot);
                dot = fmaf(w2r[o4 * 4 + 2], h.z, dot);
                dot = fmaf(w2r[o4 * 4 + 3], h.w, dot);
            }
            mx = fmaxf(mx, fmaxf(0.f, fmaf(dot, s2, bb2)));
        }
        resT[lane][w * 8 + p] = mx;
        __syncthreads();
    }
    for (int i = tid; i < 64 * 32; i += 256) {
        int o2 = i >> 5, pp = i & 31;
        out[((size_t)b * 64 + o2) * NNN + n0 + pp] = resT[o2][pp];
    }
}

extern "C" void kernel_launch(void* const* d_in, const int* in_sizes, int n_in,
                              void* d_out, int out_size, void* d_ws, size_t ws_size,
                              hipStream_t stream) {
    const float* x   = (const float*)d_in[0];
    const float* w1  = (const float*)d_in[1];
    const float* g1  = (const float*)d_in[2];
    const float* be1 = (const float*)d_in[3];
    const float* m1  = (const float*)d_in[4];
    const float* v1  = (const float*)d_in[5];
    const float* w2  = (const float*)d_in[6];
    const float* g2  = (const float*)d_in[7];
    const float* be2 = (const float*)d_in[8];
    const float* m2  = (const float*)d_in[9];
    const float* v2  = (const float*)d_in[10];
    // ws layout: xx f64 (128KB) | A f32 (4MB) | Bv f32 (4MB) | idx i32 (1.25MB)
    char* ws = (char*)d_ws;
    double* xx = (double*)ws;
    float*  A  = (float*)(ws + 131072);
    float*  Bv = (float*)(ws + 131072 + 4194304);
    int*    nidx = (int*)(ws + 131072 + 2 * 4194304);
    float*  out = (float*)d_out;

    hipLaunchKernelGGL(xx_kernel,   dim3(BB * NNN / 256), dim3(256), 0, stream, x, xx);
    hipLaunchKernelGGL(proj_kernel, dim3(BB * (NNN / 64)), dim3(256), 0, stream, x, w1, A, Bv);
    hipLaunchKernelGGL(knn_kernel,  dim3(BB * (NNN / 16)), dim3(256), 0, stream, x, xx, nidx);
    hipLaunchKernelGGL(edge_kernel, dim3(BB * (NNN / 32)), dim3(256), 0, stream,
                       A, Bv, nidx, w2, g1, be1, m1, v1, g2, be2, m2, v2, out);
}